// Round 1
// baseline (683.169 us; speedup 1.0000x reference)
//
#include <hip/hip_runtime.h>

#define N_  128
#define IC_ 3
#define OC_ 16
#define H_  256
#define W_  256
#define OH_ 254
#define OW_ 254

// mish(x) = x * tanh(softplus(x)) = x * (t-1)/(t+1), t = (1+e^x)^2
__device__ __forceinline__ float mish_f(float x) {
    float e = __expf(x);
    float p = 1.0f + e;
    float t = p * p;
    float r = x * (t - 1.0f) * __builtin_amdgcn_rcpf(t + 1.0f);
    return (x > 20.0f) ? x : r;   // avoid inf/inf for large x
}

__global__ __launch_bounds__(256) void conv_mish_kernel(
    const float* __restrict__ x, const float* __restrict__ w,
    const float* __restrict__ bias, float* __restrict__ out)
{
    // weights repacked [ic][kh][kw][oc] so 16 consecutive oc are contiguous (float4 LDS reads)
    __shared__ float sw[27 * 16];
    __shared__ float sb[16];
    int t = threadIdx.x;
    for (int i = t; i < 432; i += 256) {
        int oc = i / 27;            // w layout [oc][ic][kh][kw]
        int r  = i - oc * 27;       // r = ic*9 + kh*3 + kw
        sw[r * 16 + oc] = w[i];
    }
    if (t < 16) sb[t] = bias[t];
    __syncthreads();

    int p    = t & 127;             // pair index along ow
    int row2 = t >> 7;              // 0/1: which of the 2 rows this block covers
    int oh   = blockIdx.x * 2 + row2;
    int n    = blockIdx.y;
    if (p >= 127) return;           // 127 pairs cover ow 0..253
    int ow0  = p * 2;

    float acc0[16], acc1[16];
    #pragma unroll
    for (int oc = 0; oc < 16; ++oc) { float b = sb[oc]; acc0[oc] = b; acc1[oc] = b; }

    const float* xb = x + (size_t)n * (IC_ * H_ * W_);

    // rolled over (ic,kh) so only 48 weight floats are live at a time
    #pragma unroll 1
    for (int s = 0; s < 9; ++s) {
        int ic = s / 3;
        int kh = s - ic * 3;
        const float* rowp = xb + ic * (H_ * W_) + (oh + kh) * W_ + ow0;
        float2 a  = *(const float2*)(rowp);      // cols ow0..ow0+1 (8B aligned)
        float2 b2 = *(const float2*)(rowp + 2);  // cols ow0+2..ow0+3
        float in0 = a.x, in1 = a.y, in2 = b2.x, in3 = b2.y;
        const float4* wbase = (const float4*)(&sw[s * 48]);
        #pragma unroll
        for (int kw = 0; kw < 3; ++kw) {
            float i0 = (kw == 0) ? in0 : (kw == 1) ? in1 : in2;
            float i1 = (kw == 0) ? in1 : (kw == 1) ? in2 : in3;
            #pragma unroll
            for (int q = 0; q < 4; ++q) {
                float4 wv = wbase[kw * 4 + q];   // broadcast ds_read_b128
                acc0[q*4+0] += wv.x * i0;  acc1[q*4+0] += wv.x * i1;
                acc0[q*4+1] += wv.y * i0;  acc1[q*4+1] += wv.y * i1;
                acc0[q*4+2] += wv.z * i0;  acc1[q*4+2] += wv.z * i1;
                acc0[q*4+3] += wv.w * i0;  acc1[q*4+3] += wv.w * i1;
            }
        }
    }

    float* ob = out + (size_t)n * (OC_ * OH_ * OW_) + (size_t)oh * OW_ + ow0;
    #pragma unroll
    for (int oc = 0; oc < 16; ++oc) {
        float v0 = mish_f(mish_f(acc0[oc]));
        float v1 = mish_f(mish_f(acc1[oc]));
        *(float2*)(ob + (size_t)oc * (OH_ * OW_)) = make_float2(v0, v1);
    }
}

extern "C" void kernel_launch(void* const* d_in, const int* in_sizes, int n_in,
                              void* d_out, int out_size, void* d_ws, size_t ws_size,
                              hipStream_t stream) {
    const float* x = (const float*)d_in[0];
    const float* w = (const float*)d_in[1];
    const float* b = (const float*)d_in[2];
    float* o = (float*)d_out;
    dim3 grid(OH_ / 2, N_);   // (127, 128)
    dim3 block(256);
    conv_mish_kernel<<<grid, block, 0, stream>>>(x, w, b, o);
}